// Round 7
// baseline (2255.434 us; speedup 1.0000x reference)
//
#include <hip/hip_runtime.h>
#include <cstdint>
#include <cstddef>

#define B_   64
#define T_   300
#define DIN_ 768
#define D_   300
#define E_   8
#define NTOK (B_*T_)   // 19200
#define CH   9600      // expert token chunk (2 chunks)

typedef __attribute__((ext_vector_type(8))) short bf8_t;           // 8 bf16 (4 VGPR)
typedef __attribute__((ext_vector_type(8))) unsigned short us8_t;  // 16B copy unit
typedef __attribute__((ext_vector_type(4))) float f4_t;            // 4 fp32 acc

__device__ __forceinline__ unsigned short f2bf(float v) {
  union { float f; unsigned u; } a; a.f = v;
  unsigned r = a.u + 0x7fff + ((a.u >> 16) & 1);   // RNE
  return (unsigned short)(r >> 16);
}
__device__ __forceinline__ float bf2f(unsigned short s) {
  union { float f; unsigned u; } a; a.u = ((unsigned)s) << 16; return a.f;
}
// v ~= p0 + p1 + p2 (24 mantissa bits)
__device__ __forceinline__ void split3(float v, unsigned short& p0,
                                       unsigned short& p1, unsigned short& p2) {
  p0 = f2bf(v);
  float r1 = v - bf2f(p0);
  p1 = f2bf(r1);
  float r2 = r1 - bf2f(p1);
  p2 = f2bf(r2);
}

// ---------------------------------------------------------------------------
__global__ void biasproj_kernel(const float* __restrict__ wh_bias,
                                const float* __restrict__ wh_W,
                                float* __restrict__ bp) {
  int o = blockIdx.x * blockDim.x + threadIdx.x;
  if (o >= D_) return;
  float acc = 0.f;
  const float* row = wh_W + (size_t)o * DIN_;
  for (int d = 0; d < DIN_; ++d) acc += wh_bias[d] * row[d];
  bp[o] = -acc;
}

// ---------------------------------------------------------------------------
// split fp32 [rows][K] -> 3 bf16 planes [rows][Kp], zero-padded cols
// ---------------------------------------------------------------------------
__global__ void split_pad(const float* __restrict__ src, unsigned short* __restrict__ dst,
                          int rows, int K, int Kp, size_t planeStride) {
  int n = rows * Kp;
  for (int i = blockIdx.x * blockDim.x + threadIdx.x; i < n; i += gridDim.x * blockDim.x) {
    int r = i / Kp, c = i % Kp;
    unsigned short p0 = 0, p1 = 0, p2 = 0;
    if (c < K) split3(src[(size_t)r * K + c], p0, p1, p2);
    dst[i] = p0;
    dst[planeStride + i] = p1;
    dst[2 * planeStride + i] = p2;
  }
}

// ---------------------------------------------------------------------------
// MFMA GEMM, fp32 emulated via 3 bf16 planes (6 products).
// C[M,N] = A[M,K]*B[N,K]^T + epilogue.
// Template: AFP (A fp32 split-on-stage vs pre-split planes),
//           JN  (b-frags per wave: wave covers JN*16 cols; tile N = JN*32),
//           WM  (waves per block: 2 -> tile M=64, 4 -> tile M=128).
// B always pre-split planes (ld=Kp, zero-padded cols, rows clamped on stage).
// M must be a multiple of tile M. K-step 32.
// EPI: 0 = C = acc (+bias if non-null)        [fp32 out]
//      1 = planes(relu(acc+bias)) -> Po       [G1 -> h planes]
//      2 = gsum = g*eo, esum = eo             (eo = acc+bias)
//      3 = gsum += g*eo, esum += eo
//      4 = C = (gsum+g*eo)*(esum+eo)
//      5 = planes(acc+bias) -> Po             [whiten -> xw planes]
//      6 = C = acc+bias AND planes -> Po      [proj -> xa + xa planes]
// Plane epilogues write ZERO planes for N <= col < ldPo (pad must be defined:
// NaN*0=NaN in downstream MFMA otherwise).
// ---------------------------------------------------------------------------
#define LSTR 40
template<int AFP, int EPI, int JN, int WM>
__global__ __launch_bounds__(WM * 64, 2) void mfma_gen(
    const void* __restrict__ Av, size_t aPStride, int ldA,
    const unsigned short* __restrict__ Bg, size_t bPStride,
    const float* __restrict__ bias, float* __restrict__ C,
    unsigned short* __restrict__ Po, size_t poStride, int ldPo,
    float* __restrict__ gsum, float* __restrict__ esum,
    const float* __restrict__ gate,
    int M, int N, int K) {
  constexpr int TILE_M = WM * 32;            // 64 or 128
  constexpr int BROWS  = JN * 32;            // B rows staged = tile N
  constexpr int RB     = (WM * 64) / BROWS;  // threads per B row (1/2/4)
  constexpr int CPR    = 32 / RB;            // shorts per thread per B row
  __shared__ unsigned short Ap[3][TILE_M * LSTR];
  __shared__ unsigned short Bp[3][BROWS * LSTR];
  const int tid = threadIdx.x;
  const int bm = blockIdx.y * TILE_M, bn = blockIdx.x * BROWS;
  const int widx = tid >> 6;
  const int wr = (widx >> 1) * 64;           // 0 when WM=2
  const int wc = (widx & 1) * (JN * 16);
  const int lane = tid & 63;
  const int lr = lane & 15;
  const int kg = lane >> 4;
  const int fo = kg * 8;
  const int Kp = (K + 31) & ~31;

  f4_t acc[4][JN];
  #pragma unroll
  for (int i = 0; i < 4; ++i)
    #pragma unroll
    for (int j = 0; j < JN; ++j) acc[i][j] = (f4_t){0.f, 0.f, 0.f, 0.f};

  for (int k0 = 0; k0 < Kp; k0 += 32) {
    // ---- stage A (2 threads per row always) ----
    if constexpr (AFP) {
      const int row = tid >> 1, half = (tid & 1) * 16;
      const float* Arow = (const float*)Av + (size_t)(bm + row) * ldA + k0 + half;
      #pragma unroll
      for (int u = 0; u < 4; ++u) {
        float4 q = *(const float4*)&Arow[u * 4];
        float vv[4] = {q.x, q.y, q.z, q.w};
        unsigned short s0[4], s1[4], s2[4];
        #pragma unroll
        for (int w = 0; w < 4; ++w) split3(vv[w], s0[w], s1[w], s2[w]);
        const int so = row * LSTR + half + u * 4;
        *(unsigned*)&Ap[0][so]     = (unsigned)s0[0] | ((unsigned)s0[1] << 16);
        *(unsigned*)&Ap[0][so + 2] = (unsigned)s0[2] | ((unsigned)s0[3] << 16);
        *(unsigned*)&Ap[1][so]     = (unsigned)s1[0] | ((unsigned)s1[1] << 16);
        *(unsigned*)&Ap[1][so + 2] = (unsigned)s1[2] | ((unsigned)s1[3] << 16);
        *(unsigned*)&Ap[2][so]     = (unsigned)s2[0] | ((unsigned)s2[1] << 16);
        *(unsigned*)&Ap[2][so + 2] = (unsigned)s2[2] | ((unsigned)s2[3] << 16);
      }
    } else {
      const unsigned short* Ag = (const unsigned short*)Av;
      const int row = tid >> 1, half = (tid & 1) * 16;
      const size_t gb = (size_t)(bm + row) * Kp + k0 + half;
      const int so = row * LSTR + half;
      #pragma unroll
      for (int p = 0; p < 3; ++p) {
        us8_t v0 = *(const us8_t*)&Ag[p * aPStride + gb];
        us8_t v1 = *(const us8_t*)&Ag[p * aPStride + gb + 8];
        *(us8_t*)&Ap[p][so]     = v0;
        *(us8_t*)&Ap[p][so + 8] = v1;
      }
    }
    // ---- stage B (planes; row clamped, OOB rows feed dead cols) ----
    {
      const int brow_l = tid / RB;
      const int bq = (tid % RB) * CPR;
      int brow = bn + brow_l; if (brow >= N) brow = N - 1;
      const size_t gb = (size_t)brow * Kp + k0 + bq;
      const int so = brow_l * LSTR + bq;
      #pragma unroll
      for (int p = 0; p < 3; ++p)
        #pragma unroll
        for (int u = 0; u < CPR / 8; ++u)
          *(us8_t*)&Bp[p][so + u * 8] = *(const us8_t*)&Bg[p * bPStride + gb + u * 8];
    }
    __syncthreads();
    // ---- fragments + 6-product MFMA ----
    bf8_t a[4][3], b[JN][3];
    #pragma unroll
    for (int i = 0; i < 4; ++i)
      #pragma unroll
      for (int p = 0; p < 3; ++p)
        a[i][p] = *(const bf8_t*)&Ap[p][(wr + i * 16 + lr) * LSTR + fo];
    #pragma unroll
    for (int j = 0; j < JN; ++j)
      #pragma unroll
      for (int p = 0; p < 3; ++p)
        b[j][p] = *(const bf8_t*)&Bp[p][(wc + j * 16 + lr) * LSTR + fo];
    #pragma unroll
    for (int i = 0; i < 4; ++i)
      #pragma unroll
      for (int j = 0; j < JN; ++j) {
        f4_t c = acc[i][j];
        c = __builtin_amdgcn_mfma_f32_16x16x32_bf16(a[i][2], b[j][0], c, 0, 0, 0);
        c = __builtin_amdgcn_mfma_f32_16x16x32_bf16(a[i][1], b[j][1], c, 0, 0, 0);
        c = __builtin_amdgcn_mfma_f32_16x16x32_bf16(a[i][0], b[j][2], c, 0, 0, 0);
        c = __builtin_amdgcn_mfma_f32_16x16x32_bf16(a[i][1], b[j][0], c, 0, 0, 0);
        c = __builtin_amdgcn_mfma_f32_16x16x32_bf16(a[i][0], b[j][1], c, 0, 0, 0);
        c = __builtin_amdgcn_mfma_f32_16x16x32_bf16(a[i][0], b[j][0], c, 0, 0, 0);
        acc[i][j] = c;
      }
    __syncthreads();
  }
  // ---- epilogue ----
  #pragma unroll
  for (int i = 0; i < 4; ++i) {
    #pragma unroll
    for (int r = 0; r < 4; ++r) {
      const int row = bm + wr + i * 16 + kg * 4 + r;
      float g = 0.f;
      if constexpr (EPI >= 2 && EPI <= 4) g = gate[(size_t)row * E_];
      #pragma unroll
      for (int j = 0; j < JN; ++j) {
        const int col = bn + wc + j * 16 + lr;
        float v = acc[i][j][r];
        if constexpr (EPI == 0) {
          if (col < N) {
            if (bias) v += bias[col];
            C[(size_t)row * N + col] = v;
          }
        } else if constexpr (EPI == 1 || EPI == 5 || EPI == 6) {
          if (col < ldPo) {
            unsigned short p0 = 0, p1 = 0, p2 = 0;
            if (col < N) {
              v += bias[col];
              if constexpr (EPI == 1) v = fmaxf(v, 0.f);
              if constexpr (EPI == 6) C[(size_t)row * N + col] = v;
              split3(v, p0, p1, p2);
            }
            size_t o = (size_t)row * ldPo + col;
            Po[o] = p0;
            Po[poStride + o] = p1;
            Po[2 * poStride + o] = p2;
          }
        } else {
          if (col < N) {
            float eo = v + bias[col];
            size_t idx = (size_t)row * N + col;
            if constexpr (EPI == 2) {
              gsum[idx] = g * eo;
              esum[idx] = eo;
            } else if constexpr (EPI == 3) {
              gsum[idx] += g * eo;
              esum[idx] += eo;
            } else {
              float gs = gsum[idx] + g * eo;
              float es = esum[idx] + eo;
              C[idx] = gs * es;
            }
          }
        }
      }
    }
  }
}

// ---------------------------------------------------------------------------
// Attention over fused qkv buffer [NTOK][192] (q|k|v, 64 each).
// One 64-thread block per (b,t); att written in-place over the q columns.
// ---------------------------------------------------------------------------
__global__ __launch_bounds__(64) void attn_kernel(
    const float* __restrict__ qkv, float* __restrict__ attout) {
  const int bt = blockIdx.x;
  const int b = bt / T_, t = bt % T_;
  const int lane = threadIdx.x;
  const int h = lane >> 4, li = lane & 15;
  __shared__ float p[4][304];
  __shared__ float qs[64];
  qs[lane] = qkv[(size_t)bt * 192 + lane];
  __syncthreads();
  const float scale = rsqrtf((float)D_);
  const float* kbase = qkv + (size_t)b * T_ * 192 + 64 + h * 16;
  float mmax = -1e30f;
  for (int s = li; s <= t; s += 16) {
    const float* kr = kbase + (size_t)s * 192;
    float acc = 0.f;
    #pragma unroll
    for (int d = 0; d < 16; ++d) acc += qs[h * 16 + d] * kr[d];
    acc *= scale;
    p[h][s] = acc;
    mmax = fmaxf(mmax, acc);
  }
  #pragma unroll
  for (int m = 8; m >= 1; m >>= 1) mmax = fmaxf(mmax, __shfl_xor(mmax, m, 16));
  float lsum = 0.f;
  for (int s = li; s <= t; s += 16) {
    float e = __expf(p[h][s] - mmax);
    p[h][s] = e;
    lsum += e;
  }
  #pragma unroll
  for (int m = 8; m >= 1; m >>= 1) lsum += __shfl_xor(lsum, m, 16);
  const float inv = 1.0f / lsum;
  const float* vcol = qkv + (size_t)b * T_ * 192 + 128 + h * 16 + li;
  float o = 0.f;
  for (int s = 0; s <= t; ++s) o += p[h][s] * vcol[(size_t)s * 192];
  attout[(size_t)bt * 192 + lane] = o * inv;
}

// ---------------------------------------------------------------------------
__global__ void logits_kernel(const float* __restrict__ xa,
                              const float* __restrict__ w_gate,
                              float* __restrict__ logits) {
  int idx = blockIdx.x * blockDim.x + threadIdx.x;
  if (idx >= NTOK * E_) return;
  int n = idx >> 3, e = idx & 7;
  const float* xr = xa + (size_t)n * D_;
  float acc = 0.f;
  for (int d = 0; d < D_; ++d) acc += xr[d] * w_gate[(size_t)d * E_ + e];
  logits[idx] = acc;
}

// ---------------------------------------------------------------------------
__global__ void gate_kernel(const float* __restrict__ logits,
                            float* __restrict__ gprob) {
  int n = blockIdx.x * blockDim.x + threadIdx.x;
  if (n >= NTOK) return;
  float l[E_];
  #pragma unroll
  for (int e = 0; e < E_; ++e) l[e] = logits[(size_t)n * E_ + e];
  bool sel[E_] = {false, false, false, false, false, false, false, false};
  for (int kk = 0; kk < E_ / 2; ++kk) {
    int bi = -1; float bv = -1e38f;
    #pragma unroll
    for (int e = 0; e < E_; ++e)
      if (!sel[e] && l[e] > bv) { bv = l[e]; bi = e; }
    sel[bi] = true;
  }
  float mx = -1e38f;
  #pragma unroll
  for (int e = 0; e < E_; ++e) if (sel[e]) mx = fmaxf(mx, l[e]);
  float s = 0.f, pp[E_];
  #pragma unroll
  for (int e = 0; e < E_; ++e) {
    pp[e] = sel[e] ? __expf(l[e] - mx) : 0.f;
    s += pp[e];
  }
  float inv = 1.0f / s;
  #pragma unroll
  for (int e = 0; e < E_; ++e) gprob[(size_t)n * E_ + e] = pp[e] * inv;
}

// ---------------------------------------------------------------------------
extern "C" void kernel_launch(void* const* d_in, const int* in_sizes, int n_in,
                              void* d_out, int out_size, void* d_ws, size_t ws_size,
                              hipStream_t stream) {
  const float* x       = (const float*)d_in[0];
  const float* wh_bias = (const float*)d_in[1];
  const float* wh_W    = (const float*)d_in[2];
  const float* Wq      = (const float*)d_in[3];
  const float* Wk      = (const float*)d_in[4];
  const float* Wv      = (const float*)d_in[5];
  const float* proj_W  = (const float*)d_in[6];
  const float* proj_b  = (const float*)d_in[7];
  const float* exp_W1  = (const float*)d_in[8];
  const float* exp_b1  = (const float*)d_in[9];
  const float* exp_W2  = (const float*)d_in[10];
  const float* exp_b2  = (const float*)d_in[11];
  const float* w_gate  = (const float*)d_in[12];
  (void)in_sizes; (void)n_in; (void)out_size; (void)ws_size;

  char* ws = (char*)d_ws;
  size_t off = 0;
  auto alloc = [&](size_t bytes) {
    void* p = ws + off; off = (off + bytes + 255) & ~(size_t)255; return p;
  };
  typedef unsigned short us;
  float* bp    = (float*)alloc(300 * 4);
  us* whp      = (us*)alloc((size_t)3 * 300 * 768 * 2);          // Kp=768
  us* qkvp     = (us*)alloc((size_t)3 * 192 * 320 * 2);          // Wq|Wk|Wv, Kp=320
  us* projp    = (us*)alloc((size_t)3 * 300 * 64 * 2);           // Kp=64
  us* w1p      = (us*)alloc((size_t)3 * 4800 * 320 * 2);         // Kp=320
  us* w2p      = (us*)alloc(((size_t)3 * 2400 * 608 + 64 * 608) * 2);  // Kp=608 +guard
  float* gprob = (float*)alloc((size_t)NTOK * E_ * 4);
  us* xwreg    = (us*)alloc((size_t)3 * NTOK * 320 * 2);   // xw planes / xa fp32 / h planes
  float* qkvb  = (float*)alloc((size_t)NTOK * 192 * 4);    // qkv+att; esum in expert phase
  us* xap      = (us*)alloc((size_t)3 * NTOK * 320 * 2);   // xa planes
  // total ~108.9 MB == round-6 proven minimum. gsum lives in d_out.

  float* xa = (float*)xwreg;         // [NTOK][300] fp32; dead after gating
  us* hpl   = xwreg;                 // h planes [CH][608]x3 in expert phase
  float* esum = qkvb;                // [CH][300] fp32 (11.5MB <= 14.75MB)

  // --- weight pre-split ---
  biasproj_kernel<<<2, 256, 0, stream>>>(wh_bias, wh_W, bp);
  auto SP = [&](const float* s, us* dbase, int rows, int K, int Kp, size_t pstr) {
    int n = rows * Kp;
    int g = (n + 255) / 256; if (g > 4096) g = 4096;
    split_pad<<<g, 256, 0, stream>>>(s, dbase, rows, K, Kp, pstr);
  };
  SP(wh_W,   whp,              300,  768, 768, (size_t)300 * 768);
  SP(Wq,     qkvp,             64,   300, 320, (size_t)192 * 320);
  SP(Wk,     qkvp + 64 * 320,  64,   300, 320, (size_t)192 * 320);
  SP(Wv,     qkvp + 128 * 320, 64,   300, 320, (size_t)192 * 320);
  SP(proj_W, projp,            300,  64,  64,  (size_t)300 * 64);
  SP(exp_W1, w1p,              4800, 300, 320, (size_t)4800 * 320);
  SP(exp_W2, w2p,              2400, 600, 608, (size_t)2400 * 608);

  // --- K1: whiten -> xw planes (128x128 tiles) ---
  {
    dim3 g(3, NTOK / 128);
    mfma_gen<1, 5, 4, 4><<<g, 256, 0, stream>>>(
        x, 0, DIN_, whp, (size_t)300 * 768, bp, nullptr,
        xwreg, (size_t)NTOK * 320, 320, nullptr, nullptr, nullptr,
        NTOK, D_, DIN_);
  }
  // --- K2: fused QKV [NTOK][192] (128x64 tiles, N=192 exact) ---
  {
    dim3 g(3, NTOK / 128);
    mfma_gen<0, 0, 2, 4><<<g, 256, 0, stream>>>(
        xwreg, (size_t)NTOK * 320, 0, qkvp, (size_t)192 * 320, nullptr, qkvb,
        nullptr, 0, 0, nullptr, nullptr, nullptr,
        NTOK, 192, D_);
  }
  // --- K3: attention (att in-place over q part) ---
  attn_kernel<<<NTOK, 64, 0, stream>>>(qkvb, qkvb);

  // --- K4: proj -> xa fp32 + xa planes (128x128 tiles) ---
  {
    dim3 g(3, NTOK / 128);
    mfma_gen<1, 6, 4, 4><<<g, 256, 0, stream>>>(
        qkvb, 0, 192, projp, (size_t)300 * 64, proj_b, xa,
        xap, (size_t)NTOK * 320, 320, nullptr, nullptr, nullptr,
        NTOK, D_, 64);
  }
  // --- K5/K6: gating ---
  logits_kernel<<<(NTOK * E_ + 255) / 256, 256, 0, stream>>>(xa, w_gate, gprob);
  gate_kernel<<<(NTOK + 255) / 256, 256, 0, stream>>>(gprob, gprob);

  // --- K7: experts; gsum in d_out, esum in dead qkv buffer ---
  for (int c = 0; c < NTOK / CH; ++c) {
    const int tok0 = c * CH;
    float* gsum = (float*)d_out + (size_t)tok0 * D_;
    dim3 g1(5, CH / 128);   // G1: 128x128 tiles, N=600 (640 span)
    dim3 g2(3, CH / 64);    // G2: 64x128 tiles,  N=300 (384 span)
    for (int e = 0; e < E_; ++e) {
      const us* w1e = w1p + (size_t)e * 600 * 320;
      const us* w2e = w2p + (size_t)e * 300 * 608;
      const float* bb1 = exp_b1 + (size_t)e * 600;
      const float* bb2 = exp_b2 + (size_t)e * D_;
      const float* gate = gprob + (size_t)tok0 * E_ + e;
      // G1: h_planes = split3(relu(xa @ W1^T + b1)), pads zeroed
      mfma_gen<0, 1, 4, 4><<<g1, 256, 0, stream>>>(
          xap + (size_t)tok0 * 320, (size_t)NTOK * 320, 0,
          w1e, (size_t)4800 * 320, bb1, nullptr,
          hpl, (size_t)CH * 608, 608, nullptr, nullptr, nullptr,
          CH, 600, D_);
      // G2: eo = h @ W2^T + b2 folded into gsum/esum (final e writes out)
      if (e == 0)
        mfma_gen<0, 2, 4, 2><<<g2, 128, 0, stream>>>(
            hpl, (size_t)CH * 608, 0, w2e, (size_t)2400 * 608, bb2, nullptr,
            nullptr, 0, 0, gsum, esum, gate, CH, D_, 600);
      else if (e < E_ - 1)
        mfma_gen<0, 3, 4, 2><<<g2, 128, 0, stream>>>(
            hpl, (size_t)CH * 608, 0, w2e, (size_t)2400 * 608, bb2, nullptr,
            nullptr, 0, 0, gsum, esum, gate, CH, D_, 600);
      else
        mfma_gen<0, 4, 4, 2><<<g2, 128, 0, stream>>>(
            hpl, (size_t)CH * 608, 0, w2e, (size_t)2400 * 608, bb2,
            (float*)d_out + (size_t)tok0 * D_,
            nullptr, 0, 0, gsum, esum, gate, CH, D_, 600);
    }
  }
}

// Round 8
// 1980.053 us; speedup vs baseline: 1.1391x; 1.1391x over previous
//
#include <hip/hip_runtime.h>
#include <cstdint>
#include <cstddef>

#define B_   64
#define T_   300
#define DIN_ 768
#define D_   300
#define E_   8
#define NTOK (B_*T_)   // 19200
#define CH   9600      // expert token chunk (2 chunks)

typedef __attribute__((ext_vector_type(8))) short bf8_t;           // 8 bf16 (4 VGPR)
typedef __attribute__((ext_vector_type(8))) unsigned short us8_t;  // 16B copy unit
typedef __attribute__((ext_vector_type(4))) float f4_t;            // 4 fp32 acc

__device__ __forceinline__ unsigned short f2bf(float v) {
  union { float f; unsigned u; } a; a.f = v;
  unsigned r = a.u + 0x7fff + ((a.u >> 16) & 1);   // RNE
  return (unsigned short)(r >> 16);
}
__device__ __forceinline__ float bf2f(unsigned short s) {
  union { float f; unsigned u; } a; a.u = ((unsigned)s) << 16; return a.f;
}
// v ~= p0 + p1 + p2 (24 mantissa bits)
__device__ __forceinline__ void split3(float v, unsigned short& p0,
                                       unsigned short& p1, unsigned short& p2) {
  p0 = f2bf(v);
  float r1 = v - bf2f(p0);
  p1 = f2bf(r1);
  float r2 = r1 - bf2f(p1);
  p2 = f2bf(r2);
}

// ---------------------------------------------------------------------------
__global__ void biasproj_kernel(const float* __restrict__ wh_bias,
                                const float* __restrict__ wh_W,
                                float* __restrict__ bp) {
  int o = blockIdx.x * blockDim.x + threadIdx.x;
  if (o >= D_) return;
  float acc = 0.f;
  const float* row = wh_W + (size_t)o * DIN_;
  for (int d = 0; d < DIN_; ++d) acc += wh_bias[d] * row[d];
  bp[o] = -acc;
}

// ---------------------------------------------------------------------------
// split fp32 [rows][K] -> 3 bf16 planes [rows][Kp], zero-padded cols
// ---------------------------------------------------------------------------
__global__ void split_pad(const float* __restrict__ src, unsigned short* __restrict__ dst,
                          int rows, int K, int Kp, size_t planeStride) {
  int n = rows * Kp;
  for (int i = blockIdx.x * blockDim.x + threadIdx.x; i < n; i += gridDim.x * blockDim.x) {
    int r = i / Kp, c = i % Kp;
    unsigned short p0 = 0, p1 = 0, p2 = 0;
    if (c < K) split3(src[(size_t)r * K + c], p0, p1, p2);
    dst[i] = p0;
    dst[planeStride + i] = p1;
    dst[2 * planeStride + i] = p2;
  }
}

// ---------------------------------------------------------------------------
// MFMA GEMM, fp32 emulated via 3 bf16 planes (6 products).
// C[M,N] = A[M,K]*B[N,K]^T + epilogue.
// AFP: A fp32 split-on-stage (1) vs pre-split planes (0).
// JN:  b-frags per wave (wave spans JN*16 cols; tile N = JN*32).
// WM:  waves per block (tile M = WM*32).
// B always pre-split planes (ld=Kp, zero-padded cols, rows clamped on stage).
// M must be a multiple of tile M. K-step 32.
// EPI: 0 = C = acc (+bias if non-null)        [fp32 out]
//      1 = planes(relu(acc+bias)) -> Po       [G1 -> h planes]
//      2 = gsum = g*eo, esum = eo             (eo = acc+bias)
//      3 = gsum += g*eo, esum += eo
//      4 = C = (gsum+g*eo)*(esum+eo)
//      5 = planes(acc+bias) -> Po             [whiten -> xw planes]
//      6 = C = acc+bias AND planes -> Po      [proj -> xa + xa planes]
// Plane epilogues write ZERO planes for N <= col < ldPo (pad must be defined:
// NaN*0=NaN in downstream MFMA otherwise).
// ---------------------------------------------------------------------------
#define LSTR 40
template<int AFP, int EPI, int JN, int WM>
__global__ __launch_bounds__(WM * 64) void mfma_gen(
    const void* __restrict__ Av, size_t aPStride, int ldA,
    const unsigned short* __restrict__ Bg, size_t bPStride,
    const float* __restrict__ bias, float* __restrict__ C,
    unsigned short* __restrict__ Po, size_t poStride, int ldPo,
    float* __restrict__ gsum, float* __restrict__ esum,
    const float* __restrict__ gate,
    int M, int N, int K) {
  constexpr int TILE_M = WM * 32;            // 64 or 128
  constexpr int BROWS  = JN * 32;            // B rows staged = tile N
  constexpr int RB     = (WM * 64) / BROWS;  // threads per B row
  constexpr int CPR    = 32 / RB;            // shorts per thread per B row
  __shared__ unsigned short Ap[3][TILE_M * LSTR];
  __shared__ unsigned short Bp[3][BROWS * LSTR];
  const int tid = threadIdx.x;
  const int bm = blockIdx.y * TILE_M, bn = blockIdx.x * BROWS;
  const int widx = tid >> 6;
  const int wr = (widx >> 1) * 64;           // 0 when WM=2
  const int wc = (widx & 1) * (JN * 16);
  const int lane = tid & 63;
  const int lr = lane & 15;
  const int kg = lane >> 4;
  const int fo = kg * 8;
  const int Kp = (K + 31) & ~31;

  f4_t acc[4][JN];
  #pragma unroll
  for (int i = 0; i < 4; ++i)
    #pragma unroll
    for (int j = 0; j < JN; ++j) acc[i][j] = (f4_t){0.f, 0.f, 0.f, 0.f};

  for (int k0 = 0; k0 < Kp; k0 += 32) {
    // ---- stage A (2 threads per row) ----
    if constexpr (AFP) {
      const int row = tid >> 1, half = (tid & 1) * 16;
      const float* Arow = (const float*)Av + (size_t)(bm + row) * ldA + k0 + half;
      #pragma unroll
      for (int u = 0; u < 4; ++u) {
        float4 q = *(const float4*)&Arow[u * 4];
        float vv[4] = {q.x, q.y, q.z, q.w};
        unsigned short s0[4], s1[4], s2[4];
        #pragma unroll
        for (int w = 0; w < 4; ++w) split3(vv[w], s0[w], s1[w], s2[w]);
        const int so = row * LSTR + half + u * 4;
        *(unsigned*)&Ap[0][so]     = (unsigned)s0[0] | ((unsigned)s0[1] << 16);
        *(unsigned*)&Ap[0][so + 2] = (unsigned)s0[2] | ((unsigned)s0[3] << 16);
        *(unsigned*)&Ap[1][so]     = (unsigned)s1[0] | ((unsigned)s1[1] << 16);
        *(unsigned*)&Ap[1][so + 2] = (unsigned)s1[2] | ((unsigned)s1[3] << 16);
        *(unsigned*)&Ap[2][so]     = (unsigned)s2[0] | ((unsigned)s2[1] << 16);
        *(unsigned*)&Ap[2][so + 2] = (unsigned)s2[2] | ((unsigned)s2[3] << 16);
      }
    } else {
      const unsigned short* Ag = (const unsigned short*)Av;
      const int row = tid >> 1, half = (tid & 1) * 16;
      const size_t gb = (size_t)(bm + row) * Kp + k0 + half;
      const int so = row * LSTR + half;
      #pragma unroll
      for (int p = 0; p < 3; ++p) {
        us8_t v0 = *(const us8_t*)&Ag[p * aPStride + gb];
        us8_t v1 = *(const us8_t*)&Ag[p * aPStride + gb + 8];
        *(us8_t*)&Ap[p][so]     = v0;
        *(us8_t*)&Ap[p][so + 8] = v1;
      }
    }
    // ---- stage B (planes; row clamped, OOB rows feed dead cols) ----
    {
      const int brow_l = tid / RB;
      const int bq = (tid % RB) * CPR;
      int brow = bn + brow_l; if (brow >= N) brow = N - 1;
      const size_t gb = (size_t)brow * Kp + k0 + bq;
      const int so = brow_l * LSTR + bq;
      #pragma unroll
      for (int p = 0; p < 3; ++p)
        #pragma unroll
        for (int u = 0; u < CPR / 8; ++u)
          *(us8_t*)&Bp[p][so + u * 8] = *(const us8_t*)&Bg[p * bPStride + gb + u * 8];
    }
    __syncthreads();
    // ---- fragments + 6-product MFMA ----
    bf8_t a[4][3], b[JN][3];
    #pragma unroll
    for (int i = 0; i < 4; ++i)
      #pragma unroll
      for (int p = 0; p < 3; ++p)
        a[i][p] = *(const bf8_t*)&Ap[p][(wr + i * 16 + lr) * LSTR + fo];
    #pragma unroll
    for (int j = 0; j < JN; ++j)
      #pragma unroll
      for (int p = 0; p < 3; ++p)
        b[j][p] = *(const bf8_t*)&Bp[p][(wc + j * 16 + lr) * LSTR + fo];
    #pragma unroll
    for (int i = 0; i < 4; ++i)
      #pragma unroll
      for (int j = 0; j < JN; ++j) {
        f4_t c = acc[i][j];
        c = __builtin_amdgcn_mfma_f32_16x16x32_bf16(a[i][2], b[j][0], c, 0, 0, 0);
        c = __builtin_amdgcn_mfma_f32_16x16x32_bf16(a[i][1], b[j][1], c, 0, 0, 0);
        c = __builtin_amdgcn_mfma_f32_16x16x32_bf16(a[i][0], b[j][2], c, 0, 0, 0);
        c = __builtin_amdgcn_mfma_f32_16x16x32_bf16(a[i][1], b[j][0], c, 0, 0, 0);
        c = __builtin_amdgcn_mfma_f32_16x16x32_bf16(a[i][0], b[j][1], c, 0, 0, 0);
        c = __builtin_amdgcn_mfma_f32_16x16x32_bf16(a[i][0], b[j][0], c, 0, 0, 0);
        acc[i][j] = c;
      }
    __syncthreads();
  }
  // ---- epilogue ----
  #pragma unroll
  for (int i = 0; i < 4; ++i) {
    #pragma unroll
    for (int r = 0; r < 4; ++r) {
      const int row = bm + wr + i * 16 + kg * 4 + r;
      float g = 0.f;
      if constexpr (EPI >= 2 && EPI <= 4) g = gate[(size_t)row * E_];
      #pragma unroll
      for (int j = 0; j < JN; ++j) {
        const int col = bn + wc + j * 16 + lr;
        float v = acc[i][j][r];
        if constexpr (EPI == 0) {
          if (col < N) {
            if (bias) v += bias[col];
            C[(size_t)row * N + col] = v;
          }
        } else if constexpr (EPI == 1 || EPI == 5 || EPI == 6) {
          if (col < ldPo) {
            unsigned short p0 = 0, p1 = 0, p2 = 0;
            if (col < N) {
              v += bias[col];
              if constexpr (EPI == 1) v = fmaxf(v, 0.f);
              if constexpr (EPI == 6) C[(size_t)row * N + col] = v;
              split3(v, p0, p1, p2);
            }
            size_t o = (size_t)row * ldPo + col;
            Po[o] = p0;
            Po[poStride + o] = p1;
            Po[2 * poStride + o] = p2;
          }
        } else {
          if (col < N) {
            float eo = v + bias[col];
            size_t idx = (size_t)row * N + col;
            if constexpr (EPI == 2) {
              gsum[idx] = g * eo;
              esum[idx] = eo;
            } else if constexpr (EPI == 3) {
              gsum[idx] += g * eo;
              esum[idx] += eo;
            } else {
              float gs = gsum[idx] + g * eo;
              float es = esum[idx] + eo;
              C[idx] = gs * es;
            }
          }
        }
      }
    }
  }
}

// ---------------------------------------------------------------------------
// Attention over fused qkv buffer [NTOK][192] (q|k|v, 64 each).
// One 64-thread block per (b,t); att written in-place over the q columns.
// PV uses 4 accumulators to break the 300-long dependent FMA chain.
// ---------------------------------------------------------------------------
__global__ __launch_bounds__(64) void attn_kernel(
    const float* __restrict__ qkv, float* __restrict__ attout) {
  const int bt = blockIdx.x;
  const int b = bt / T_, t = bt % T_;
  const int lane = threadIdx.x;
  const int h = lane >> 4, li = lane & 15;
  __shared__ float p[4][304];
  __shared__ float qs[64];
  qs[lane] = qkv[(size_t)bt * 192 + lane];
  __syncthreads();
  const float scale = rsqrtf((float)D_);
  const float* kbase = qkv + (size_t)b * T_ * 192 + 64 + h * 16;
  float mmax = -1e30f;
  for (int s = li; s <= t; s += 16) {
    const float* kr = kbase + (size_t)s * 192;
    float acc = 0.f;
    #pragma unroll
    for (int d = 0; d < 16; ++d) acc += qs[h * 16 + d] * kr[d];
    acc *= scale;
    p[h][s] = acc;
    mmax = fmaxf(mmax, acc);
  }
  #pragma unroll
  for (int m = 8; m >= 1; m >>= 1) mmax = fmaxf(mmax, __shfl_xor(mmax, m, 16));
  float lsum = 0.f;
  for (int s = li; s <= t; s += 16) {
    float e = __expf(p[h][s] - mmax);
    p[h][s] = e;
    lsum += e;
  }
  #pragma unroll
  for (int m = 8; m >= 1; m >>= 1) lsum += __shfl_xor(lsum, m, 16);
  const float inv = 1.0f / lsum;
  const float* vcol = qkv + (size_t)b * T_ * 192 + 128 + h * 16 + li;
  float o0 = 0.f, o1 = 0.f, o2 = 0.f, o3 = 0.f;
  int s = 0;
  for (; s + 4 <= t + 1; s += 4) {
    o0 += p[h][s]     * vcol[(size_t)s * 192];
    o1 += p[h][s + 1] * vcol[(size_t)(s + 1) * 192];
    o2 += p[h][s + 2] * vcol[(size_t)(s + 2) * 192];
    o3 += p[h][s + 3] * vcol[(size_t)(s + 3) * 192];
  }
  for (; s <= t; ++s) o0 += p[h][s] * vcol[(size_t)s * 192];
  attout[(size_t)bt * 192 + lane] = ((o0 + o1) + (o2 + o3)) * inv;
}

// ---------------------------------------------------------------------------
__global__ void logits_kernel(const float* __restrict__ xa,
                              const float* __restrict__ w_gate,
                              float* __restrict__ logits) {
  int idx = blockIdx.x * blockDim.x + threadIdx.x;
  if (idx >= NTOK * E_) return;
  int n = idx >> 3, e = idx & 7;
  const float* xr = xa + (size_t)n * D_;
  float acc = 0.f;
  for (int d = 0; d < D_; ++d) acc += xr[d] * w_gate[(size_t)d * E_ + e];
  logits[idx] = acc;
}

// ---------------------------------------------------------------------------
__global__ void gate_kernel(const float* __restrict__ logits,
                            float* __restrict__ gprob) {
  int n = blockIdx.x * blockDim.x + threadIdx.x;
  if (n >= NTOK) return;
  float l[E_];
  #pragma unroll
  for (int e = 0; e < E_; ++e) l[e] = logits[(size_t)n * E_ + e];
  bool sel[E_] = {false, false, false, false, false, false, false, false};
  for (int kk = 0; kk < E_ / 2; ++kk) {
    int bi = -1; float bv = -1e38f;
    #pragma unroll
    for (int e = 0; e < E_; ++e)
      if (!sel[e] && l[e] > bv) { bv = l[e]; bi = e; }
    sel[bi] = true;
  }
  float mx = -1e38f;
  #pragma unroll
  for (int e = 0; e < E_; ++e) if (sel[e]) mx = fmaxf(mx, l[e]);
  float s = 0.f, pp[E_];
  #pragma unroll
  for (int e = 0; e < E_; ++e) {
    pp[e] = sel[e] ? __expf(l[e] - mx) : 0.f;
    s += pp[e];
  }
  float inv = 1.0f / s;
  #pragma unroll
  for (int e = 0; e < E_; ++e) gprob[(size_t)n * E_ + e] = pp[e] * inv;
}

// ---------------------------------------------------------------------------
extern "C" void kernel_launch(void* const* d_in, const int* in_sizes, int n_in,
                              void* d_out, int out_size, void* d_ws, size_t ws_size,
                              hipStream_t stream) {
  const float* x       = (const float*)d_in[0];
  const float* wh_bias = (const float*)d_in[1];
  const float* wh_W    = (const float*)d_in[2];
  const float* Wq      = (const float*)d_in[3];
  const float* Wk      = (const float*)d_in[4];
  const float* Wv      = (const float*)d_in[5];
  const float* proj_W  = (const float*)d_in[6];
  const float* proj_b  = (const float*)d_in[7];
  const float* exp_W1  = (const float*)d_in[8];
  const float* exp_b1  = (const float*)d_in[9];
  const float* exp_W2  = (const float*)d_in[10];
  const float* exp_b2  = (const float*)d_in[11];
  const float* w_gate  = (const float*)d_in[12];
  (void)in_sizes; (void)n_in; (void)out_size; (void)ws_size;

  char* ws = (char*)d_ws;
  size_t off = 0;
  auto alloc = [&](size_t bytes) {
    void* p = ws + off; off = (off + bytes + 255) & ~(size_t)255; return p;
  };
  typedef unsigned short us;
  float* bp    = (float*)alloc(300 * 4);
  us* whp      = (us*)alloc((size_t)3 * 300 * 768 * 2);          // Kp=768
  us* qkvp     = (us*)alloc((size_t)3 * 192 * 320 * 2);          // Wq|Wk|Wv, Kp=320
  us* projp    = (us*)alloc((size_t)3 * 300 * 64 * 2);           // Kp=64
  us* w1p      = (us*)alloc((size_t)3 * 4800 * 320 * 2);         // Kp=320
  us* w2p      = (us*)alloc(((size_t)3 * 2400 * 608 + 64 * 608) * 2);  // Kp=608 +guard
  float* gprob = (float*)alloc((size_t)NTOK * E_ * 4);
  us* xwreg    = (us*)alloc((size_t)3 * NTOK * 320 * 2);   // xw planes / xa fp32 / h planes
  float* qkvb  = (float*)alloc((size_t)NTOK * 192 * 4);    // qkv+att; esum in expert phase
  us* xap      = (us*)alloc((size_t)3 * NTOK * 320 * 2);   // xa planes
  // total ~108.9 MB == round-6 proven footprint. gsum lives in d_out.

  float* xa = (float*)xwreg;         // [NTOK][300] fp32; dead after gating
  us* hpl   = xwreg;                 // h planes [CH][608]x3 in expert phase
  float* esum = qkvb;                // [CH][300] fp32 (11.5MB <= 14.75MB)

  // --- weight pre-split ---
  biasproj_kernel<<<2, 256, 0, stream>>>(wh_bias, wh_W, bp);
  auto SP = [&](const float* s, us* dbase, int rows, int K, int Kp, size_t pstr) {
    int n = rows * Kp;
    int g = (n + 255) / 256; if (g > 4096) g = 4096;
    split_pad<<<g, 256, 0, stream>>>(s, dbase, rows, K, Kp, pstr);
  };
  SP(wh_W,   whp,              300,  768, 768, (size_t)300 * 768);
  SP(Wq,     qkvp,             64,   300, 320, (size_t)192 * 320);
  SP(Wk,     qkvp + 64 * 320,  64,   300, 320, (size_t)192 * 320);
  SP(Wv,     qkvp + 128 * 320, 64,   300, 320, (size_t)192 * 320);
  SP(proj_W, projp,            300,  64,  64,  (size_t)300 * 64);
  SP(exp_W1, w1p,              4800, 300, 320, (size_t)4800 * 320);
  SP(exp_W2, w2p,              2400, 600, 608, (size_t)2400 * 608);

  // --- K1: whiten -> xw planes (128x64 tiles, round-6 shape) ---
  {
    dim3 g(5, NTOK / 128);
    mfma_gen<1, 5, 2, 4><<<g, 256, 0, stream>>>(
        x, 0, DIN_, whp, (size_t)300 * 768, bp, nullptr,
        xwreg, (size_t)NTOK * 320, 320, nullptr, nullptr, nullptr,
        NTOK, D_, DIN_);
  }
  // --- K2: fused QKV [NTOK][192] (128x64 tiles, N=192 exact) ---
  {
    dim3 g(3, NTOK / 128);
    mfma_gen<0, 0, 2, 4><<<g, 256, 0, stream>>>(
        xwreg, (size_t)NTOK * 320, 0, qkvp, (size_t)192 * 320, nullptr, qkvb,
        nullptr, 0, 0, nullptr, nullptr, nullptr,
        NTOK, 192, D_);
  }
  // --- K3: attention (att in-place over q part) ---
  attn_kernel<<<NTOK, 64, 0, stream>>>(qkvb, qkvb);

  // --- K4: proj -> xa fp32 + xa planes (128x64 tiles, round-6 shape) ---
  {
    dim3 g(5, NTOK / 128);
    mfma_gen<1, 6, 2, 4><<<g, 256, 0, stream>>>(
        qkvb, 0, 192, projp, (size_t)300 * 64, proj_b, xa,
        xap, (size_t)NTOK * 320, 320, nullptr, nullptr, nullptr,
        NTOK, D_, 64);
  }
  // --- K5/K6: gating ---
  logits_kernel<<<(NTOK * E_ + 255) / 256, 256, 0, stream>>>(xa, w_gate, gprob);
  gate_kernel<<<(NTOK + 255) / 256, 256, 0, stream>>>(gprob, gprob);

  // --- K7: experts; gsum in d_out, esum in dead qkv buffer ---
  for (int c = 0; c < NTOK / CH; ++c) {
    const int tok0 = c * CH;
    float* gsum = (float*)d_out + (size_t)tok0 * D_;
    dim3 g1(5, CH / 128);   // G1 ARM: 128x128 tiles (64x64/wave), N=600/640 span
    dim3 g2(5, CH / 128);   // G2: 128x64 tiles (round-6 shape), N=300/320 span
    for (int e = 0; e < E_; ++e) {
      const us* w1e = w1p + (size_t)e * 600 * 320;
      const us* w2e = w2p + (size_t)e * 300 * 608;
      const float* bb1 = exp_b1 + (size_t)e * 600;
      const float* bb2 = exp_b2 + (size_t)e * D_;
      const float* gate = gprob + (size_t)tok0 * E_ + e;
      // G1: h_planes = split3(relu(xa @ W1^T + b1)), pads zeroed
      mfma_gen<0, 1, 4, 4><<<g1, 256, 0, stream>>>(
          xap + (size_t)tok0 * 320, (size_t)NTOK * 320, 0,
          w1e, (size_t)4800 * 320, bb1, nullptr,
          hpl, (size_t)CH * 608, 608, nullptr, nullptr, nullptr,
          CH, 600, D_);
      // G2: eo = h @ W2^T + b2 folded into gsum/esum (final e writes out)
      if (e == 0)
        mfma_gen<0, 2, 2, 4><<<g2, 256, 0, stream>>>(
            hpl, (size_t)CH * 608, 0, w2e, (size_t)2400 * 608, bb2, nullptr,
            nullptr, 0, 0, gsum, esum, gate, CH, D_, 600);
      else if (e < E_ - 1)
        mfma_gen<0, 3, 2, 4><<<g2, 256, 0, stream>>>(
            hpl, (size_t)CH * 608, 0, w2e, (size_t)2400 * 608, bb2, nullptr,
            nullptr, 0, 0, gsum, esum, gate, CH, D_, 600);
      else
        mfma_gen<0, 4, 2, 4><<<g2, 256, 0, stream>>>(
            hpl, (size_t)CH * 608, 0, w2e, (size_t)2400 * 608, bb2,
            (float*)d_out + (size_t)tok0 * D_,
            nullptr, 0, 0, gsum, esum, gate, CH, D_, 600);
    }
  }
}

// Round 9
// 1537.831 us; speedup vs baseline: 1.4666x; 1.2876x over previous
//
#include <hip/hip_runtime.h>
#include <cstdint>
#include <cstddef>

#define B_   64
#define T_   300
#define DIN_ 768
#define D_   300
#define E_   8
#define NTOK (B_*T_)   // 19200
#define CH   9600      // expert token chunk (2 chunks)

typedef __attribute__((ext_vector_type(8))) short bf8_t;           // 8 bf16 (4 VGPR)
typedef __attribute__((ext_vector_type(8))) unsigned short us8_t;  // 16B copy unit
typedef __attribute__((ext_vector_type(4))) float f4_t;            // 4 fp32 acc

__device__ __forceinline__ unsigned short f2bf(float v) {
  union { float f; unsigned u; } a; a.f = v;
  unsigned r = a.u + 0x7fff + ((a.u >> 16) & 1);   // RNE
  return (unsigned short)(r >> 16);
}
__device__ __forceinline__ float bf2f(unsigned short s) {
  union { float f; unsigned u; } a; a.u = ((unsigned)s) << 16; return a.f;
}
// v ~= p0 + p1 + p2 (24 mantissa bits)
__device__ __forceinline__ void split3(float v, unsigned short& p0,
                                       unsigned short& p1, unsigned short& p2) {
  p0 = f2bf(v);
  float r1 = v - bf2f(p0);
  p1 = f2bf(r1);
  float r2 = r1 - bf2f(p1);
  p2 = f2bf(r2);
}
// v ~= p0 + p1 (17 mantissa bits)
__device__ __forceinline__ void split2(float v, unsigned short& p0,
                                       unsigned short& p1) {
  p0 = f2bf(v);
  p1 = f2bf(v - bf2f(p0));
}

// ---------------------------------------------------------------------------
__global__ void biasproj_kernel(const float* __restrict__ wh_bias,
                                const float* __restrict__ wh_W,
                                float* __restrict__ bp) {
  int o = blockIdx.x * blockDim.x + threadIdx.x;
  if (o >= D_) return;
  float acc = 0.f;
  const float* row = wh_W + (size_t)o * DIN_;
  for (int d = 0; d < DIN_; ++d) acc += wh_bias[d] * row[d];
  bp[o] = -acc;
}

// ---------------------------------------------------------------------------
// split fp32 [rows][K] -> np bf16 planes [rows][Kp], zero-padded cols
// ---------------------------------------------------------------------------
__global__ void split_pad(const float* __restrict__ src, unsigned short* __restrict__ dst,
                          int rows, int K, int Kp, size_t planeStride, int np) {
  int n = rows * Kp;
  for (int i = blockIdx.x * blockDim.x + threadIdx.x; i < n; i += gridDim.x * blockDim.x) {
    int r = i / Kp, c = i % Kp;
    unsigned short p0 = 0, p1 = 0, p2 = 0;
    if (c < K) split3(src[(size_t)r * K + c], p0, p1, p2);
    dst[i] = p0;
    dst[planeStride + i] = p1;
    if (np == 3) dst[2 * planeStride + i] = p2;
  }
}

// ---------------------------------------------------------------------------
// MFMA GEMM, fp32 emulated via NP bf16 planes (NP=3: 6 products; NP=2: 3).
// C[M,N] = A[M,K]*B[N,K]^T + epilogue.
// AFP: A fp32 split3-on-stage (requires NP=3) vs pre-split NP planes.
// JN:  b-frags per wave (wave spans JN*16 cols; tile N = JN*32).
// WM:  waves per block (tile M = WM*32).
// NPO: plane count written by plane epilogues (1/5/6).
// B always pre-split planes (ld=Kp, zero-padded cols, rows clamped on stage).
// M must be a multiple of tile M. K-step 32.
// EPI: 0 = C = acc (+bias if non-null)        [fp32 out]
//      1 = planes(relu(acc+bias)) -> Po       [G1 -> h planes]
//      2 = gsum = g*eo, esum = eo             (eo = acc+bias)
//      3 = gsum += g*eo, esum += eo
//      4 = C = (gsum+g*eo)*(esum+eo)
//      5 = planes(acc+bias) -> Po             [whiten -> xw planes]
//      6 = C = acc+bias AND planes -> Po      [proj -> xa + xa planes]
// Plane epilogues write ZERO planes for N <= col < ldPo (pad must be defined:
// NaN*0=NaN in downstream MFMA otherwise).
// ---------------------------------------------------------------------------
#define LSTR 40
template<int AFP, int EPI, int JN, int WM, int NP, int NPO>
__global__ __launch_bounds__(WM * 64) void mfma_gen(
    const void* __restrict__ Av, size_t aPStride, int ldA,
    const unsigned short* __restrict__ Bg, size_t bPStride,
    const float* __restrict__ bias, float* __restrict__ C,
    unsigned short* __restrict__ Po, size_t poStride, int ldPo,
    float* __restrict__ gsum, float* __restrict__ esum,
    const float* __restrict__ gate,
    int M, int N, int K) {
  constexpr int TILE_M = WM * 32;            // 64 or 128
  constexpr int BROWS  = JN * 32;            // B rows staged = tile N
  constexpr int RB     = (WM * 64) / BROWS;  // threads per B row
  constexpr int CPR    = 32 / RB;            // shorts per thread per B row
  __shared__ unsigned short Ap[NP][TILE_M * LSTR];
  __shared__ unsigned short Bp[NP][BROWS * LSTR];
  const int tid = threadIdx.x;
  const int bm = blockIdx.y * TILE_M, bn = blockIdx.x * BROWS;
  const int widx = tid >> 6;
  const int wr = (widx >> 1) * 64;           // 0 when WM=2
  const int wc = (widx & 1) * (JN * 16);
  const int lane = tid & 63;
  const int lr = lane & 15;
  const int kg = lane >> 4;
  const int fo = kg * 8;
  const int Kp = (K + 31) & ~31;

  f4_t acc[4][JN];
  #pragma unroll
  for (int i = 0; i < 4; ++i)
    #pragma unroll
    for (int j = 0; j < JN; ++j) acc[i][j] = (f4_t){0.f, 0.f, 0.f, 0.f};

  for (int k0 = 0; k0 < Kp; k0 += 32) {
    // ---- stage A (2 threads per row) ----
    if constexpr (AFP) {
      static_assert(!AFP || NP == 3, "AFP path writes 3 planes");
      const int row = tid >> 1, half = (tid & 1) * 16;
      const float* Arow = (const float*)Av + (size_t)(bm + row) * ldA + k0 + half;
      #pragma unroll
      for (int u = 0; u < 4; ++u) {
        float4 q = *(const float4*)&Arow[u * 4];
        float vv[4] = {q.x, q.y, q.z, q.w};
        unsigned short s0[4], s1[4], s2[4];
        #pragma unroll
        for (int w = 0; w < 4; ++w) split3(vv[w], s0[w], s1[w], s2[w]);
        const int so = row * LSTR + half + u * 4;
        *(unsigned*)&Ap[0][so]     = (unsigned)s0[0] | ((unsigned)s0[1] << 16);
        *(unsigned*)&Ap[0][so + 2] = (unsigned)s0[2] | ((unsigned)s0[3] << 16);
        *(unsigned*)&Ap[1][so]     = (unsigned)s1[0] | ((unsigned)s1[1] << 16);
        *(unsigned*)&Ap[1][so + 2] = (unsigned)s1[2] | ((unsigned)s1[3] << 16);
        *(unsigned*)&Ap[2][so]     = (unsigned)s2[0] | ((unsigned)s2[1] << 16);
        *(unsigned*)&Ap[2][so + 2] = (unsigned)s2[2] | ((unsigned)s2[3] << 16);
      }
    } else {
      const unsigned short* Ag = (const unsigned short*)Av;
      const int row = tid >> 1, half = (tid & 1) * 16;
      const size_t gb = (size_t)(bm + row) * Kp + k0 + half;
      const int so = row * LSTR + half;
      #pragma unroll
      for (int p = 0; p < NP; ++p) {
        us8_t v0 = *(const us8_t*)&Ag[p * aPStride + gb];
        us8_t v1 = *(const us8_t*)&Ag[p * aPStride + gb + 8];
        *(us8_t*)&Ap[p][so]     = v0;
        *(us8_t*)&Ap[p][so + 8] = v1;
      }
    }
    // ---- stage B (planes; row clamped, OOB rows feed dead cols) ----
    {
      const int brow_l = tid / RB;
      const int bq = (tid % RB) * CPR;
      int brow = bn + brow_l; if (brow >= N) brow = N - 1;
      const size_t gb = (size_t)brow * Kp + k0 + bq;
      const int so = brow_l * LSTR + bq;
      #pragma unroll
      for (int p = 0; p < NP; ++p)
        #pragma unroll
        for (int u = 0; u < CPR / 8; ++u)
          *(us8_t*)&Bp[p][so + u * 8] = *(const us8_t*)&Bg[p * bPStride + gb + u * 8];
    }
    __syncthreads();
    // ---- fragments + cross-product MFMA ----
    bf8_t a[4][NP], b[JN][NP];
    #pragma unroll
    for (int i = 0; i < 4; ++i)
      #pragma unroll
      for (int p = 0; p < NP; ++p)
        a[i][p] = *(const bf8_t*)&Ap[p][(wr + i * 16 + lr) * LSTR + fo];
    #pragma unroll
    for (int j = 0; j < JN; ++j)
      #pragma unroll
      for (int p = 0; p < NP; ++p)
        b[j][p] = *(const bf8_t*)&Bp[p][(wc + j * 16 + lr) * LSTR + fo];
    #pragma unroll
    for (int i = 0; i < 4; ++i)
      #pragma unroll
      for (int j = 0; j < JN; ++j) {
        f4_t c = acc[i][j];
        if constexpr (NP == 3) {
          c = __builtin_amdgcn_mfma_f32_16x16x32_bf16(a[i][2], b[j][0], c, 0, 0, 0);
          c = __builtin_amdgcn_mfma_f32_16x16x32_bf16(a[i][1], b[j][1], c, 0, 0, 0);
          c = __builtin_amdgcn_mfma_f32_16x16x32_bf16(a[i][0], b[j][2], c, 0, 0, 0);
          c = __builtin_amdgcn_mfma_f32_16x16x32_bf16(a[i][1], b[j][0], c, 0, 0, 0);
          c = __builtin_amdgcn_mfma_f32_16x16x32_bf16(a[i][0], b[j][1], c, 0, 0, 0);
          c = __builtin_amdgcn_mfma_f32_16x16x32_bf16(a[i][0], b[j][0], c, 0, 0, 0);
        } else {
          c = __builtin_amdgcn_mfma_f32_16x16x32_bf16(a[i][1], b[j][0], c, 0, 0, 0);
          c = __builtin_amdgcn_mfma_f32_16x16x32_bf16(a[i][0], b[j][1], c, 0, 0, 0);
          c = __builtin_amdgcn_mfma_f32_16x16x32_bf16(a[i][0], b[j][0], c, 0, 0, 0);
        }
        acc[i][j] = c;
      }
    __syncthreads();
  }
  // ---- epilogue ----
  #pragma unroll
  for (int i = 0; i < 4; ++i) {
    #pragma unroll
    for (int r = 0; r < 4; ++r) {
      const int row = bm + wr + i * 16 + kg * 4 + r;
      float g = 0.f;
      if constexpr (EPI >= 2 && EPI <= 4) g = gate[(size_t)row * E_];
      #pragma unroll
      for (int j = 0; j < JN; ++j) {
        const int col = bn + wc + j * 16 + lr;
        float v = acc[i][j][r];
        if constexpr (EPI == 0) {
          if (col < N) {
            if (bias) v += bias[col];
            C[(size_t)row * N + col] = v;
          }
        } else if constexpr (EPI == 1 || EPI == 5 || EPI == 6) {
          if (col < ldPo) {
            unsigned short p0 = 0, p1 = 0, p2 = 0;
            if (col < N) {
              v += bias[col];
              if constexpr (EPI == 1) v = fmaxf(v, 0.f);
              if constexpr (EPI == 6) C[(size_t)row * N + col] = v;
              if constexpr (NPO == 3) split3(v, p0, p1, p2);
              else                    split2(v, p0, p1);
            }
            size_t o = (size_t)row * ldPo + col;
            Po[o] = p0;
            Po[poStride + o] = p1;
            if constexpr (NPO == 3) Po[2 * poStride + o] = p2;
          }
        } else {
          if (col < N) {
            float eo = v + bias[col];
            size_t idx = (size_t)row * N + col;
            if constexpr (EPI == 2) {
              gsum[idx] = g * eo;
              esum[idx] = eo;
            } else if constexpr (EPI == 3) {
              gsum[idx] += g * eo;
              esum[idx] += eo;
            } else {
              float gs = gsum[idx] + g * eo;
              float es = esum[idx] + eo;
              C[idx] = gs * es;
            }
          }
        }
      }
    }
  }
}

// ---------------------------------------------------------------------------
// Attention over fused qkv buffer [NTOK][192] (q|k|v, 64 each).
// One 64-thread block per (b,t); att written in-place over the q columns.
// ---------------------------------------------------------------------------
__global__ __launch_bounds__(64) void attn_kernel(
    const float* __restrict__ qkv, float* __restrict__ attout) {
  const int bt = blockIdx.x;
  const int b = bt / T_, t = bt % T_;
  const int lane = threadIdx.x;
  const int h = lane >> 4, li = lane & 15;
  __shared__ float p[4][304];
  __shared__ float qs[64];
  qs[lane] = qkv[(size_t)bt * 192 + lane];
  __syncthreads();
  const float scale = rsqrtf((float)D_);
  const float* kbase = qkv + (size_t)b * T_ * 192 + 64 + h * 16;
  float mmax = -1e30f;
  for (int s = li; s <= t; s += 16) {
    const float* kr = kbase + (size_t)s * 192;
    float acc = 0.f;
    #pragma unroll
    for (int d = 0; d < 16; ++d) acc += qs[h * 16 + d] * kr[d];
    acc *= scale;
    p[h][s] = acc;
    mmax = fmaxf(mmax, acc);
  }
  #pragma unroll
  for (int m = 8; m >= 1; m >>= 1) mmax = fmaxf(mmax, __shfl_xor(mmax, m, 16));
  float lsum = 0.f;
  for (int s = li; s <= t; s += 16) {
    float e = __expf(p[h][s] - mmax);
    p[h][s] = e;
    lsum += e;
  }
  #pragma unroll
  for (int m = 8; m >= 1; m >>= 1) lsum += __shfl_xor(lsum, m, 16);
  const float inv = 1.0f / lsum;
  const float* vcol = qkv + (size_t)b * T_ * 192 + 128 + h * 16 + li;
  float o0 = 0.f, o1 = 0.f, o2 = 0.f, o3 = 0.f;
  int s = 0;
  for (; s + 4 <= t + 1; s += 4) {
    o0 += p[h][s]     * vcol[(size_t)s * 192];
    o1 += p[h][s + 1] * vcol[(size_t)(s + 1) * 192];
    o2 += p[h][s + 2] * vcol[(size_t)(s + 2) * 192];
    o3 += p[h][s + 3] * vcol[(size_t)(s + 3) * 192];
  }
  for (; s <= t; ++s) o0 += p[h][s] * vcol[(size_t)s * 192];
  attout[(size_t)bt * 192 + lane] = ((o0 + o1) + (o2 + o3)) * inv;
}

// ---------------------------------------------------------------------------
__global__ void logits_kernel(const float* __restrict__ xa,
                              const float* __restrict__ w_gate,
                              float* __restrict__ logits) {
  int idx = blockIdx.x * blockDim.x + threadIdx.x;
  if (idx >= NTOK * E_) return;
  int n = idx >> 3, e = idx & 7;
  const float* xr = xa + (size_t)n * D_;
  float acc = 0.f;
  for (int d = 0; d < D_; ++d) acc += xr[d] * w_gate[(size_t)d * E_ + e];
  logits[idx] = acc;
}

// ---------------------------------------------------------------------------
__global__ void gate_kernel(const float* __restrict__ logits,
                            float* __restrict__ gprob) {
  int n = blockIdx.x * blockDim.x + threadIdx.x;
  if (n >= NTOK) return;
  float l[E_];
  #pragma unroll
  for (int e = 0; e < E_; ++e) l[e] = logits[(size_t)n * E_ + e];
  bool sel[E_] = {false, false, false, false, false, false, false, false};
  for (int kk = 0; kk < E_ / 2; ++kk) {
    int bi = -1; float bv = -1e38f;
    #pragma unroll
    for (int e = 0; e < E_; ++e)
      if (!sel[e] && l[e] > bv) { bv = l[e]; bi = e; }
    sel[bi] = true;
  }
  float mx = -1e38f;
  #pragma unroll
  for (int e = 0; e < E_; ++e) if (sel[e]) mx = fmaxf(mx, l[e]);
  float s = 0.f, pp[E_];
  #pragma unroll
  for (int e = 0; e < E_; ++e) {
    pp[e] = sel[e] ? __expf(l[e] - mx) : 0.f;
    s += pp[e];
  }
  float inv = 1.0f / s;
  #pragma unroll
  for (int e = 0; e < E_; ++e) gprob[(size_t)n * E_ + e] = pp[e] * inv;
}

// ---------------------------------------------------------------------------
extern "C" void kernel_launch(void* const* d_in, const int* in_sizes, int n_in,
                              void* d_out, int out_size, void* d_ws, size_t ws_size,
                              hipStream_t stream) {
  const float* x       = (const float*)d_in[0];
  const float* wh_bias = (const float*)d_in[1];
  const float* wh_W    = (const float*)d_in[2];
  const float* Wq      = (const float*)d_in[3];
  const float* Wk      = (const float*)d_in[4];
  const float* Wv      = (const float*)d_in[5];
  const float* proj_W  = (const float*)d_in[6];
  const float* proj_b  = (const float*)d_in[7];
  const float* exp_W1  = (const float*)d_in[8];
  const float* exp_b1  = (const float*)d_in[9];
  const float* exp_W2  = (const float*)d_in[10];
  const float* exp_b2  = (const float*)d_in[11];
  const float* w_gate  = (const float*)d_in[12];
  (void)in_sizes; (void)n_in; (void)out_size; (void)ws_size;

  char* ws = (char*)d_ws;
  size_t off = 0;
  auto alloc = [&](size_t bytes) {
    void* p = ws + off; off = (off + bytes + 255) & ~(size_t)255; return p;
  };
  typedef unsigned short us;
  float* bp    = (float*)alloc(300 * 4);
  us* whp      = (us*)alloc((size_t)3 * 300 * 768 * 2);          // 3-plane, Kp=768
  us* qkvp     = (us*)alloc((size_t)2 * 192 * 320 * 2);          // 2-plane, Kp=320
  us* projp    = (us*)alloc((size_t)3 * 300 * 64 * 2);           // 3-plane, Kp=64
  us* w1p      = (us*)alloc((size_t)2 * 4800 * 320 * 2);         // 2-plane, Kp=320
  us* w2p      = (us*)alloc(((size_t)2 * 2400 * 608 + 64 * 608) * 2);  // 2-plane +guard
  float* gprob = (float*)alloc((size_t)NTOK * E_ * 4);
  us* xwreg    = (us*)alloc((size_t)2 * NTOK * 320 * 2);   // xw 2-plane / xa fp32 / h 2-plane
  float* qkvb  = (float*)alloc((size_t)NTOK * 192 * 4);    // qkv+att; esum in expert phase
  us* xap      = (us*)alloc((size_t)2 * NTOK * 320 * 2);   // xa 2-plane
  // total ~78 MB (< round-6 proven 108.9 MB). gsum lives in d_out.

  float* xa = (float*)xwreg;         // [NTOK][300] fp32; dead after gating
  us* hpl   = xwreg;                 // h planes [CH][608]x2 in expert phase (23.3MB<=24.6MB)
  float* esum = qkvb;                // [CH][300] fp32 (11.5MB <= 14.75MB)

  // --- weight pre-split ---
  biasproj_kernel<<<2, 256, 0, stream>>>(wh_bias, wh_W, bp);
  auto SP = [&](const float* s, us* dbase, int rows, int K, int Kp, size_t pstr, int np) {
    int n = rows * Kp;
    int g = (n + 255) / 256; if (g > 4096) g = 4096;
    split_pad<<<g, 256, 0, stream>>>(s, dbase, rows, K, Kp, pstr, np);
  };
  SP(wh_W,   whp,              300,  768, 768, (size_t)300 * 768, 3);
  SP(Wq,     qkvp,             64,   300, 320, (size_t)192 * 320, 2);
  SP(Wk,     qkvp + 64 * 320,  64,   300, 320, (size_t)192 * 320, 2);
  SP(Wv,     qkvp + 128 * 320, 64,   300, 320, (size_t)192 * 320, 2);
  SP(proj_W, projp,            300,  64,  64,  (size_t)300 * 64, 3);
  SP(exp_W1, w1p,              4800, 300, 320, (size_t)4800 * 320, 2);
  SP(exp_W2, w2p,              2400, 600, 608, (size_t)2400 * 608, 2);

  // --- K1: whiten (3-plane math) -> xw 2-plane ---
  {
    dim3 g(5, NTOK / 128);
    mfma_gen<1, 5, 2, 4, 3, 2><<<g, 256, 0, stream>>>(
        x, 0, DIN_, whp, (size_t)300 * 768, bp, nullptr,
        xwreg, (size_t)NTOK * 320, 320, nullptr, nullptr, nullptr,
        NTOK, D_, DIN_);
  }
  // --- K2: fused QKV [NTOK][192], 2-plane both sides ---
  {
    dim3 g(3, NTOK / 128);
    mfma_gen<0, 0, 2, 4, 2, 2><<<g, 256, 0, stream>>>(
        xwreg, (size_t)NTOK * 320, 0, qkvp, (size_t)192 * 320, nullptr, qkvb,
        nullptr, 0, 0, nullptr, nullptr, nullptr,
        NTOK, 192, D_);
  }
  // --- K3: attention (att in-place over q part) ---
  attn_kernel<<<NTOK, 64, 0, stream>>>(qkvb, qkvb);

  // --- K4: proj (3-plane math) -> xa fp32 + xa 2-plane ---
  {
    dim3 g(5, NTOK / 128);
    mfma_gen<1, 6, 2, 4, 3, 2><<<g, 256, 0, stream>>>(
        qkvb, 0, 192, projp, (size_t)300 * 64, proj_b, xa,
        xap, (size_t)NTOK * 320, 320, nullptr, nullptr, nullptr,
        NTOK, D_, 64);
  }
  // --- K5/K6: gating ---
  logits_kernel<<<(NTOK * E_ + 255) / 256, 256, 0, stream>>>(xa, w_gate, gprob);
  gate_kernel<<<(NTOK + 255) / 256, 256, 0, stream>>>(gprob, gprob);

  // --- K7: experts (2-plane); gsum in d_out, esum in dead qkv buffer ---
  for (int c = 0; c < NTOK / CH; ++c) {
    const int tok0 = c * CH;
    float* gsum = (float*)d_out + (size_t)tok0 * D_;
    dim3 g1(5, CH / 128);   // G1: 128x128 tiles (2-plane -> 41KB LDS)
    dim3 g2(5, CH / 128);   // G2: 128x64 tiles
    for (int e = 0; e < E_; ++e) {
      const us* w1e = w1p + (size_t)e * 600 * 320;
      const us* w2e = w2p + (size_t)e * 300 * 608;
      const float* bb1 = exp_b1 + (size_t)e * 600;
      const float* bb2 = exp_b2 + (size_t)e * D_;
      const float* gate = gprob + (size_t)tok0 * E_ + e;
      // G1: h_2planes = split2(relu(xa @ W1^T + b1)), pads zeroed
      mfma_gen<0, 1, 4, 4, 2, 2><<<g1, 256, 0, stream>>>(
          xap + (size_t)tok0 * 320, (size_t)NTOK * 320, 0,
          w1e, (size_t)4800 * 320, bb1, nullptr,
          hpl, (size_t)CH * 608, 608, nullptr, nullptr, nullptr,
          CH, 600, D_);
      // G2: eo = h @ W2^T + b2 folded into gsum/esum (final e writes out)
      if (e == 0)
        mfma_gen<0, 2, 2, 4, 2, 2><<<g2, 256, 0, stream>>>(
            hpl, (size_t)CH * 608, 0, w2e, (size_t)2400 * 608, bb2, nullptr,
            nullptr, 0, 0, gsum, esum, gate, CH, D_, 600);
      else if (e < E_ - 1)
        mfma_gen<0, 3, 2, 4, 2, 2><<<g2, 256, 0, stream>>>(
            hpl, (size_t)CH * 608, 0, w2e, (size_t)2400 * 608, bb2, nullptr,
            nullptr, 0, 0, gsum, esum, gate, CH, D_, 600);
      else
        mfma_gen<0, 4, 2, 4, 2, 2><<<g2, 256, 0, stream>>>(
            hpl, (size_t)CH * 608, 0, w2e, (size_t)2400 * 608, bb2,
            (float*)d_out + (size_t)tok0 * D_,
            nullptr, 0, 0, gsum, esum, gate, CH, D_, 600);
    }
  }
}